// Round 11
// baseline (452.882 us; speedup 1.0000x reference)
//
#include <hip/hip_runtime.h>
#include <stdint.h>
#include <stddef.h>

// Problem constants (MultiHeadAttention_52759378264454)
constexpr int T_SEQ = 1024;
constexpr int BATCH = 8;
constexpr int DIN   = 256;
constexpr int NH    = 8;
constexpr int EH    = 512;
constexpr int HE    = NH * EH;   // 4096
constexpr int BT    = BATCH * T_SEQ;  // 8192
constexpr float SCALE = 0.044194173824159216f; // 1/sqrt(512)

typedef __attribute__((ext_vector_type(8))) short s16x8;
typedef __attribute__((ext_vector_type(4))) short s16x4;
typedef __attribute__((ext_vector_type(4))) float f32x4_t;

__device__ __forceinline__ short f2bf(float f) {
  union { float f; uint32_t u; } c; c.f = f;
  uint32_t u = c.u;
  u += 0x7fffu + ((u >> 16) & 1u);   // RNE
  return (short)(u >> 16);
}
__device__ __forceinline__ float bf2f(short s) {
  union { uint32_t u; float f; } c; c.u = ((uint32_t)(uint16_t)s) << 16;
  return c.f;
}

// async global->LDS, 16B/lane. LDS dest = wave-uniform base + lane*16 (HW).
__device__ __forceinline__ void gload16(const short* g, short* l) {
  __builtin_amdgcn_global_load_lds(
      (__attribute__((address_space(1))) void*)(void*)const_cast<short*>(g),
      (__attribute__((address_space(3))) void*)(void*)l, 16, 0, 0);
}

#define LD8(p) (*(const s16x8*)(p))

// ---------------------------------------------------------------------------
// m97-style 4-wave 128x128 GEMM core, BK=64, mfma_f32_16x16x32_bf16.
// 256 threads = 4 waves (wm = wv>>1, wn = wv&1), per-wave 64x64 = 4mi x 4ni
// of 16x16 frags (acc = 64 VGPR). Single 32 KB LDS buffer, 2 barriers per
// K-step (the proven 874-912 TF structure, m97/m103), ~3 blocks/CU.
// LDS: A[128][64] bf16 at 0 (8192 shorts), B[128][64] at 8192.
// Swizzle: row = 8 x 16B chunks; chunk cp holds source chunk cp ^ (row&7)
// (involution, applied on stage source AND read -> conflict-free b128).
// A/B frag (16x16x32): lane l: row = l&15, k = (l>>4)*8 + j (one 16B chunk).
// C/D: col = l&15, row = (l>>4)*4 + reg  [m89/m91].
// Trailing __syncthreads so callers may reuse LDS.
// ---------------------------------------------------------------------------
template<int NT>   // K = NT*64
__device__ __forceinline__ void gemm16(const short* __restrict__ Ag, int lda,
                                       const short* __restrict__ Bg, int ldb,
                                       short* lds, f32x4_t (&acc)[4][4])
{
  const int tid = threadIdx.x;
  const int l = tid & 63, wv = tid >> 6;
  const int r = l & 15, g = l >> 4;
  const int wm = wv >> 1, wn = wv & 1;

  // staging: 1024 chunks per matrix, 4 per thread (c = tid + j*256)
  const int srow = tid >> 3;                         // + j*32
  const int scol = ((tid & 7) ^ (srow & 7)) * 8;     // swizzled source chunk
  const int sdst = wv * 512;                         // + j*2048 (shorts)

  // read side
  const short* Ab = lds + (wm * 64 + r) * 64;
  const short* Bb = lds + 8192 + (wn * 64 + r) * 64;
  int xo[2];
#pragma unroll
  for (int ks = 0; ks < 2; ++ks) xo[ks] = ((ks * 4 + g) ^ (r & 7)) * 8;

#pragma unroll 1
  for (int t = 0; t < NT; ++t) {
    __syncthreads();                     // prev tile fully consumed
    const int ko = t * 64;
#pragma unroll
    for (int j = 0; j < 4; ++j)
      gload16(Ag + (size_t)(srow + j * 32) * lda + ko + scol, lds + sdst + j * 2048);
#pragma unroll
    for (int j = 0; j < 4; ++j)
      gload16(Bg + (size_t)(srow + j * 32) * ldb + ko + scol, lds + 8192 + sdst + j * 2048);
    __syncthreads();                     // vmcnt(0) drain: tile ready
#pragma unroll
    for (int ks = 0; ks < 2; ++ks) {
      s16x8 a[4], b[4];
#pragma unroll
      for (int mi = 0; mi < 4; ++mi) a[mi] = LD8(Ab + mi * 1024 + xo[ks]);
#pragma unroll
      for (int ni = 0; ni < 4; ++ni) b[ni] = LD8(Bb + ni * 1024 + xo[ks]);
      __builtin_amdgcn_s_setprio(1);
#pragma unroll
      for (int mi = 0; mi < 4; ++mi)
#pragma unroll
        for (int ni = 0; ni < 4; ++ni)
          acc[mi][ni] = __builtin_amdgcn_mfma_f32_16x16x32_bf16(a[mi], b[ni], acc[mi][ni], 0, 0, 0);
      __builtin_amdgcn_s_setprio(0);
    }
  }
  __syncthreads();                       // callers may reuse LDS
}

// C coords for 16x16 frags (4 waves 2x2)
#define CROW16(mi, reg) ((wv >> 1) * 64 + (mi) * 16 + g * 4 + (reg))
#define CCOL16(ni)      ((wv & 1) * 64 + (ni) * 16 + r)

// bounce buffer stride (shorts): 136 (= 128 + 8 pad -> ~2-way banks)
constexpr int SBS = 136;   // 128*136 = 17408 shorts = 34816 B

// ---------------------------------------------------------------------------
// K0: fused fp32->bf16 cast; Qb transposed to [b][t][d]; weights copied.
// ---------------------------------------------------------------------------
__global__ __launch_bounds__(256) void k_cvt_all(
    const float* __restrict__ Q,  const float* __restrict__ Wq,
    const float* __restrict__ Wk, const float* __restrict__ Wv,
    const float* __restrict__ Wo, short* __restrict__ dst)
{
  constexpr int N_Q = 524288;              // 1024*8*256/4
  constexpr int N_W = 262144;              // 8*512*256/4
  constexpr int TOT = N_Q + 4 * N_W;
  int i  = blockIdx.x * 256 + threadIdx.x;
  int st = gridDim.x * 256;
  for (; i < TOT; i += st) {
    const float* s; int off;
    if (i < N_Q) {
      int b = i >> 16, t = (i >> 6) & 1023, d4 = i & 63;
      s = Q; off = (t * 8 + b) * 64 + d4;
    }
    else if (i < N_Q + N_W)     { s = Wq; off = i - N_Q; }
    else if (i < N_Q + 2 * N_W) { s = Wk; off = i - N_Q - N_W; }
    else if (i < N_Q + 3 * N_W) { s = Wv; off = i - N_Q - 2 * N_W; }
    else                        { s = Wo; off = i - N_Q - 3 * N_W; }
    float4 v = ((const float4*)s)[off];
    s16x4 o = { f2bf(v.x), f2bf(v.y), f2bf(v.z), f2bf(v.w) };
    ((s16x4*)dst)[i] = o;
  }
}

// ---------------------------------------------------------------------------
// K1a: Q/K projection. C[m,e] = sum_d Qb[m,d]*W[h,e,d] + bias. NT = 4.
// 1-D grid 64*4*2HG; bx spread across XCDs.
// ---------------------------------------------------------------------------
__global__ __launch_bounds__(256) void k_projqk(
    const short* __restrict__ Qb,
    const short* __restrict__ Wqb, const short* __restrict__ Wkb,
    const float* __restrict__ bq, const float* __restrict__ bk,
    short* __restrict__ qb, short* __restrict__ kb, int h0, int HG)
{
  __shared__ short lds[17408];
  int f = blockIdx.x;
  int bx = (f & 7) + 8 * ((f >> 3) & 7);
  int rest = f >> 6;
  int by = rest & 3, zz = rest >> 2;
  int p = zz / HG, hh = zz % HG, h = h0 + hh;

  const short* W    = (p == 0 ? Wqb : Wkb) + ((size_t)h * EH + (size_t)by * 128) * DIN;
  const float* bias = (p == 0 ? bq  : bk ) + h * EH + by * 128;
  short* outp       = (p == 0 ? qb  : kb ) + (size_t)hh * BT * EH;
  const short* Ag   = Qb + (size_t)bx * 128 * DIN;

  f32x4_t acc[4][4] = {};
  gemm16<DIN / 64>(Ag, DIN, W, DIN, lds, acc);

  const int tid = threadIdx.x, l = tid & 63, wv = tid >> 6, r = l & 15, g = l >> 4;
#pragma unroll
  for (int ni = 0; ni < 4; ++ni) {
    int col = CCOL16(ni);
    float bia = bias[col];
#pragma unroll
    for (int mi = 0; mi < 4; ++mi)
#pragma unroll
      for (int reg = 0; reg < 4; ++reg)
        lds[CROW16(mi, reg) * SBS + col] = f2bf(acc[mi][ni][reg] + bia);
  }
  __syncthreads();
  int orow = tid >> 1, oseg = (tid & 1) * 64;
  const short* src = lds + orow * SBS + oseg;
  short* dst = outp + (size_t)(bx * 128 + orow) * EH + by * 128 + oseg;
#pragma unroll
  for (int j = 0; j < 8; ++j) *(s16x8*)(dst + j * 8) = LD8(src + j * 8);
}

// ---------------------------------------------------------------------------
// K1b: V projection TRANSPOSED: C[e,m] = sum_d Wv[h,e,d]*Qb[m,d] + bv[h,e]
// -> vT[hh][e][m]. 1-D grid 64*4*HG. NT = 4.
// ---------------------------------------------------------------------------
__global__ __launch_bounds__(256) void k_projv(
    const short* __restrict__ Qb, const short* __restrict__ Wvb,
    const float* __restrict__ bv, short* __restrict__ vT, int h0, int HG)
{
  __shared__ short lds[17408];
  int f = blockIdx.x;
  int bn = (f & 7) + 8 * ((f >> 3) & 7);     // m-tile [0,64)
  int rest = f >> 6;
  int be = rest & 3, hh = rest >> 2, h = h0 + hh;

  const short* Ag = Wvb + ((size_t)h * EH + (size_t)be * 128) * DIN;
  const short* Bg = Qb + (size_t)bn * 128 * DIN;

  f32x4_t acc[4][4] = {};
  gemm16<DIN / 64>(Ag, DIN, Bg, DIN, lds, acc);

  const int tid = threadIdx.x, l = tid & 63, wv = tid >> 6, r = l & 15, g = l >> 4;
  const float* bvp = bv + h * EH + be * 128;
#pragma unroll
  for (int mi = 0; mi < 4; ++mi)
#pragma unroll
    for (int reg = 0; reg < 4; ++reg) {
      int row = CROW16(mi, reg);
      float bia = bvp[row];
#pragma unroll
      for (int ni = 0; ni < 4; ++ni)
        lds[row * SBS + CCOL16(ni)] = f2bf(acc[mi][ni][reg] + bia);
    }
  __syncthreads();
  int orow = tid >> 1, oseg = (tid & 1) * 64;
  const short* src = lds + orow * SBS + oseg;
  short* dst = vT + (size_t)hh * EH * BT + (size_t)(be * 128 + orow) * BT
             + bn * 128 + oseg;
#pragma unroll
  for (int j = 0; j < 8; ++j) *(s16x8*)(dst + j * 8) = LD8(src + j * 8);
}

// ---------------------------------------------------------------------------
// K3a: P[t,s] = exp(SCALE*q.k) bf16 + per-block column sums. NT = 8.
// grid (8,8,HG*8); same-z grouped per XCD. colpart 8 partials per z.
// ---------------------------------------------------------------------------
__global__ __launch_bounds__(256) void k_pgen(
    const short* __restrict__ qb, const short* __restrict__ kb,
    short* __restrict__ Pbuf, float* __restrict__ colpart, int HG)
{
  __shared__ short lds[17408];
  int f = blockIdx.x + (blockIdx.y << 3) + (blockIdx.z << 6);
  int xcd = f & 7, rest = f >> 3;
  int zi = rest % HG, rb = rest / HG;
  int z = xcd * HG + zi;
  int bx = rb & 7, by = rb >> 3;

  const short* Ag = qb + (size_t)z * T_SEQ * EH + (size_t)bx * 128 * EH;
  const short* Bg = kb + (size_t)z * T_SEQ * EH + (size_t)by * 128 * EH;

  f32x4_t acc[4][4] = {};
  gemm16<EH / 64>(Ag, EH, Bg, EH, lds, acc);

  const int tid = threadIdx.x, l = tid & 63, wv = tid >> 6, r = l & 15, g = l >> 4;
  float cs[4] = {0.f, 0.f, 0.f, 0.f};
#pragma unroll
  for (int ni = 0; ni < 4; ++ni) {
    int col = CCOL16(ni);
#pragma unroll
    for (int mi = 0; mi < 4; ++mi)
#pragma unroll
      for (int reg = 0; reg < 4; ++reg) {
        float ev = __expf(acc[mi][ni][reg] * SCALE);
        cs[ni] += ev;
        lds[CROW16(mi, reg) * SBS + col] = f2bf(ev);
      }
  }
  // reduce over g-groups (rows within wave): lanes l, l^16, l^32, l^48
#pragma unroll
  for (int ni = 0; ni < 4; ++ni) {
    cs[ni] += __shfl_xor(cs[ni], 16);
    cs[ni] += __shfl_xor(cs[ni], 32);
  }
  __syncthreads();
  // coalesced P store
  int orow = tid >> 1, oseg = (tid & 1) * 64;
  const short* src = lds + orow * SBS + oseg;
  short* Pb = Pbuf + (size_t)z * T_SEQ * T_SEQ
            + (size_t)(bx * 128 + orow) * T_SEQ + by * 128 + oseg;
#pragma unroll
  for (int j = 0; j < 8; ++j) *(s16x8*)(Pb + j * 8) = LD8(src + j * 8);
  __syncthreads();
  // cross-wave colsum reduce (csL[2 wm][128])
  float* csL = (float*)lds;
  if (l < 16) {
#pragma unroll
    for (int ni = 0; ni < 4; ++ni) csL[(wv >> 1) * 128 + CCOL16(ni)] = cs[ni];
  }
  __syncthreads();
  if (tid < 128) {
    colpart[((size_t)z * 8 + bx) * T_SEQ + by * 128 + tid] = csL[tid] + csL[128 + tid];
  }
}

// ---------------------------------------------------------------------------
// K2: scale V in place by the softmax normalizer (fused invsum, 8 partials):
// vT[hh][e][m] *= 1 / sum_p colpart[(z*8+p)][t]
// ---------------------------------------------------------------------------
__global__ __launch_bounds__(256) void k_scalev(
    short* __restrict__ vT, const float* __restrict__ colpart, int HG)
{
  __shared__ float invL[1024];
  const int et = blockIdx.x, z = blockIdx.y;
  const int hh = z >> 3, b = z & 7;
  const int tid = threadIdx.x;

#pragma unroll
  for (int it = 0; it < 4; ++it) {
    int t = it * 256 + tid;
    float s = 0.f;
#pragma unroll
    for (int p = 0; p < 8; ++p) s += colpart[((size_t)z * 8 + p) * T_SEQ + t];
    invL[t] = 1.0f / s;
  }
  __syncthreads();

  short* base = vT + (size_t)hh * EH * BT
                   + (size_t)et * 64 * BT + (size_t)b * T_SEQ;
  for (int c = tid; c < 64 * 128; c += 256) {
    int row = c >> 7, col = (c & 127) * 8;
    short* p = &base[(size_t)row * BT + col];
    s16x8 v = *(s16x8*)p;
#pragma unroll
    for (int j = 0; j < 8; ++j) v[j] = f2bf(bf2f(v[j]) * invL[col + j]);
    *(s16x8*)p = v;
  }
}

// ---------------------------------------------------------------------------
// K3b: O[t,e] = sum_s P[t,s]*vT[e,s] -> Hmat[(b*T+t), h*EH+e]. NT = 16.
// grid (8,4,HG*8); same-z grouped per XCD.
// ---------------------------------------------------------------------------
__global__ __launch_bounds__(256) void k_ogemm(
    const short* __restrict__ Pbuf, const short* __restrict__ vT,
    short* __restrict__ Hmat, int h0, int HG)
{
  __shared__ short lds[17408];
  int f = blockIdx.x + (blockIdx.y << 3) + (blockIdx.z << 5);
  int xcd = f & 7, rest = f >> 3;
  int zi = rest % HG, rb = rest / HG;
  int z = xcd * HG + zi;
  int bx = rb & 7, by = rb >> 3;
  const int hh = z >> 3, b = z & 7, h = h0 + hh;

  const short* Ag = Pbuf + (size_t)z * T_SEQ * T_SEQ + (size_t)bx * 128 * T_SEQ;
  const short* Bg = vT + ((size_t)hh * EH + (size_t)by * 128) * BT + (size_t)b * T_SEQ;

  f32x4_t acc[4][4] = {};
  gemm16<T_SEQ / 64>(Ag, T_SEQ, Bg, BT, lds, acc);

  const int tid = threadIdx.x, l = tid & 63, wv = tid >> 6, r = l & 15, g = l >> 4;
#pragma unroll
  for (int ni = 0; ni < 4; ++ni) {
    int col = CCOL16(ni);
#pragma unroll
    for (int mi = 0; mi < 4; ++mi)
#pragma unroll
      for (int reg = 0; reg < 4; ++reg)
        lds[CROW16(mi, reg) * SBS + col] = f2bf(acc[mi][ni][reg]);
  }
  __syncthreads();
  int orow = tid >> 1, oseg = (tid & 1) * 64;
  const short* src = lds + orow * SBS + oseg;
  short* dst = Hmat + ((size_t)b * T_SEQ + bx * 128 + orow) * HE
             + (size_t)h * EH + by * 128 + oseg;
#pragma unroll
  for (int j = 0; j < 8; ++j) *(s16x8*)(dst + j * 8) = LD8(src + j * 8);
}

// ---------------------------------------------------------------------------
// K4a: split-K(4) output GEMM. part[ks][m][d], K-slice 1024, NT = 16.
// 1-D grid 512. fp32 direct store (64B segments).
// ---------------------------------------------------------------------------
__global__ __launch_bounds__(256) void k_final(
    const short* __restrict__ Hmat, const short* __restrict__ Wob,
    float* __restrict__ part)
{
  __shared__ short lds[16384];
  int f = blockIdx.x;
  int bx = (f & 7) + 8 * ((f >> 3) & 7);
  int rest = f >> 6;
  int by = rest & 1, ks = rest >> 1;

  const short* Ag = Hmat + (size_t)bx * 128 * HE + (size_t)ks * 1024;
  const short* Bg = Wob  + (size_t)by * 128 * HE + (size_t)ks * 1024;

  f32x4_t acc[4][4] = {};
  gemm16<1024 / 64>(Ag, HE, Bg, HE, lds, acc);

  float* pp = part + (size_t)ks * BT * DIN;
  const int l = threadIdx.x & 63, wv = threadIdx.x >> 6, r = l & 15, g = l >> 4;
#pragma unroll
  for (int ni = 0; ni < 4; ++ni) {
    int d = by * 128 + CCOL16(ni);
#pragma unroll
    for (int mi = 0; mi < 4; ++mi)
#pragma unroll
      for (int reg = 0; reg < 4; ++reg) {
        int m = bx * 128 + CROW16(mi, reg);
        pp[(size_t)m * DIN + d] = acc[mi][ni][reg];
      }
  }
}

// K4b: out[(t*B+b), d] = sum_ks part[ks][(b*T+t)][d] + bo[d]
__global__ __launch_bounds__(256) void k_red(const float* __restrict__ part,
                                             const float* __restrict__ bo,
                                             float* __restrict__ out)
{
  int i = blockIdx.x * 256 + threadIdx.x;   // over 8192*64 float4s
  int m = i >> 6, d4 = i & 63;
  float4 s = ((const float4*)part)[i];
#pragma unroll
  for (int ks = 1; ks < 4; ++ks) {
    float4 p = ((const float4*)(part + (size_t)ks * BT * DIN))[i];
    s.x += p.x; s.y += p.y; s.z += p.z; s.w += p.w;
  }
  float4 b4 = ((const float4*)bo)[d4];
  s.x += b4.x; s.y += b4.y; s.z += b4.z; s.w += b4.w;
  int t = m & 1023, b = m >> 10;
  ((float4*)out)[(t * 8 + b) * 64 + d4] = s;
}

// ---------------------------------------------------------------------------
extern "C" void kernel_launch(void* const* d_in, const int* in_sizes, int n_in,
                              void* d_out, int out_size, void* d_ws, size_t ws_size,
                              hipStream_t stream)
{
  const float* Q  = (const float*)d_in[0];
  const float* Wq = (const float*)d_in[1];
  const float* bq = (const float*)d_in[2];
  const float* Wk = (const float*)d_in[3];
  const float* bk = (const float*)d_in[4];
  const float* Wv = (const float*)d_in[5];
  const float* bv = (const float*)d_in[6];
  const float* Wo = (const float*)d_in[7];
  const float* bo = (const float*)d_in[8];
  float* out = (float*)d_out;

  // ---- sizes ----
  const size_t QB_B   = (size_t)BT * DIN * 2;                  //  4 MiB
  const size_t W_B    = (size_t)NH * EH * DIN * 2;             //  2 MiB each
  const size_t WO_B   = (size_t)DIN * HE * 2;                  //  2 MiB
  const size_t HMAT_B = (size_t)BT * HE * 2;                   // 64 MiB
  const size_t PART_B = (size_t)4 * BT * DIN * 4;              // 32 MiB
  const size_t QKV1   = (size_t)BT * EH * 2;                   //  8 MiB / head
  const size_t P1     = (size_t)BATCH * T_SEQ * T_SEQ * 2;     // 16 MiB / head
  const size_t CP1    = (size_t)BATCH * 8 * T_SEQ * 4;         // 256 KiB / head
  const size_t inputsB = QB_B + 3 * W_B + WO_B;                // 12 MiB contiguous

  // ---- largest HG whose plan fits (alias: part <-> P) ----
  int HG = 8;
  for (; HG > 1; HG >>= 1) {
    size_t share = ((size_t)HG * P1 > PART_B) ? (size_t)HG * P1 : PART_B;
    size_t tot = inputsB + 3 * (size_t)HG * QKV1 + share + HMAT_B
               + (size_t)HG * CP1 + 8192;
    if (tot <= ws_size) break;
  }
  size_t shareB = ((size_t)HG * P1 > PART_B) ? (size_t)HG * P1 : PART_B;

  char* w = (char*)d_ws;
  auto alloc = [&](size_t bytes) {
    char* p = w;
    w += (bytes + 255) & ~(size_t)255;
    return p;
  };
  short* Qb   = (short*)alloc(QB_B);
  short* Wqb  = (short*)alloc(W_B);
  short* Wkb  = (short*)alloc(W_B);
  short* Wvb  = (short*)alloc(W_B);
  short* Wob  = (short*)alloc(WO_B);
  float* cpart= (float*)alloc((size_t)HG * CP1);
  short* qb   = (short*)alloc((size_t)HG * QKV1);
  short* kb   = (short*)alloc((size_t)HG * QKV1);
  short* vT   = (short*)alloc((size_t)HG * QKV1);
  char*  shr  = alloc(shareB);                      // P during loop; part after
  short* Hmat = (short*)alloc(HMAT_B);

  short* Pbuf = (short*)shr;
  float* part = (float*)shr;

  k_cvt_all<<<dim3(2048), 256, 0, stream>>>(Q, Wq, Wk, Wv, Wo, Qb);

  for (int h0 = 0; h0 < NH; h0 += HG) {
    k_projqk<<<dim3(512 * HG), 256, 0, stream>>>(Qb, Wqb, Wkb, bq, bk,
                                                 qb, kb, h0, HG);
    k_projv <<<dim3(256 * HG), 256, 0, stream>>>(Qb, Wvb, bv, vT, h0, HG);
    k_pgen  <<<dim3(8, 8, HG * 8), 256, 0, stream>>>(qb, kb, Pbuf, cpart, HG);
    k_scalev<<<dim3(8, HG * 8), 256, 0, stream>>>(vT, cpart, HG);
    k_ogemm <<<dim3(8, 4, HG * 8), 256, 0, stream>>>(Pbuf, vT, Hmat, h0, HG);
  }
  k_final<<<dim3(512), 256, 0, stream>>>(Hmat, Wob, part);
  k_red  <<<dim3(BT * DIN / 4 / 256), 256, 0, stream>>>(part, bo, out);
}